// Round 10
// baseline (275.727 us; speedup 1.0000x reference)
//
#include <hip/hip_runtime.h>
#include <hip/hip_bf16.h>

// ---------------------------------------------------------------------------
// Mamba block forward. Round 10: all-bf16 intermediates (u_pre too), fused
// prep kernel, dt-GEMM moved to bf16 MFMA (K=64), GEMM1 retiled 128x64
// (1024 blocks, 4/CU). B=2 L=1024 DM=1024 DI=2048 DS=16 DTR=64
// ---------------------------------------------------------------------------

typedef __attribute__((ext_vector_type(8))) short bfrag;
typedef __attribute__((ext_vector_type(4))) float f32x4;

#define CF   32   // scan time-chunks
#define CLEN 32   // steps per chunk (CF*CLEN = 1024)

__device__ __forceinline__ unsigned short f2bf(float f) {
    unsigned int u = __float_as_uint(f);
    u += 0x7FFF + ((u >> 16) & 1);          // round-to-nearest-even
    return (unsigned short)(u >> 16);
}
__device__ __forceinline__ float bf2f(unsigned short s) {
    return __uint_as_float((unsigned int)s << 16);
}

__device__ __forceinline__ void async_copy16(const unsigned short* g,
                                             unsigned short* l) {
    __builtin_amdgcn_global_load_lds(
        (const __attribute__((address_space(1))) void*)g,
        (__attribute__((address_space(3))) void*)l, 16, 0, 0);
}

// ---------------- bf16 MFMA GEMM v2: C[M][N] = A[M][K] * BT[N][K]^T ---------
// Tile MT x NT, BK=64, 4 waves (2x2), wave does (MT/2)x(NT/2).
// XOR-swizzled unpadded LDS; global_load_lds width-16 staging.
// Epilogue: bias!=null -> softplus(v+bias[col]) -> bf16 Cb0 (ld=ldc)
//           split>0    -> col<split: bf16 Cb0 ; else bf16 Cb1 (ld=split)
//           else       -> fp32 C (ld=ldc)
template<int MT, int NT>
__global__ __launch_bounds__(256) void gemm_bf16_v2(
    const unsigned short* __restrict__ A,   // [M][K] bf16
    const unsigned short* __restrict__ BT,  // [N][K] bf16
    float* __restrict__ C,
    unsigned short* __restrict__ Cb0,
    unsigned short* __restrict__ Cb1,
    int K, int lda, int ldb, int ldc, int split,
    const float* __restrict__ bias)
{
    constexpr int FI  = MT / 32;
    constexpr int FJ  = NT / 32;
    constexpr int ACH = MT / 32;            // A 1KB-chunks per wave
    constexpr int BCH = NT / 32;
    __shared__ __align__(16) unsigned short sA[MT * 64];
    __shared__ __align__(16) unsigned short sB[NT * 64];

    const int tid  = threadIdx.x;
    const int wave = tid >> 6, lane = tid & 63;
    const int lm   = lane & 15;
    const int quad = lane >> 4;
    const int wrow = (wave >> 1) * (MT / 2);
    const int wcol = (wave & 1) * (NT / 2);
    const int bm = blockIdx.y * MT, bn = blockIdx.x * NT;

    const int lrow = lane >> 3;             // 0..7 (row within 8-row chunk)
    const int lkb  = (lane & 7) ^ lrow;     // swizzled k-block to fetch

    f32x4 acc[FI][FJ];
    #pragma unroll
    for (int i = 0; i < FI; ++i)
        #pragma unroll
        for (int j = 0; j < FJ; ++j) {
            acc[i][j][0] = 0.f; acc[i][j][1] = 0.f;
            acc[i][j][2] = 0.f; acc[i][j][3] = 0.f;
        }

    for (int k0 = 0; k0 < K; k0 += 64) {
        #pragma unroll
        for (int c = 0; c < ACH; ++c) {
            const int chunk = wave * ACH + c;
            const int row = chunk * 8 + lrow;
            async_copy16(&A[(size_t)(bm + row) * lda + k0 + lkb * 8],
                         &sA[chunk * 512 + lane * 8]);
        }
        #pragma unroll
        for (int c = 0; c < BCH; ++c) {
            const int chunk = wave * BCH + c;
            const int row = chunk * 8 + lrow;
            async_copy16(&BT[(size_t)(bn + row) * ldb + k0 + lkb * 8],
                         &sB[chunk * 512 + lane * 8]);
        }
        __syncthreads();

        #pragma unroll
        for (int ks = 0; ks < 2; ++ks) {
            bfrag af[FI], bf[FJ];
            #pragma unroll
            for (int i = 0; i < FI; ++i) {
                const int row = wrow + i * 16 + lm;
                const int slot = (ks * 4 + quad) ^ (row & 7);
                af[i] = *(const bfrag*)&sA[row * 64 + slot * 8];
            }
            #pragma unroll
            for (int j = 0; j < FJ; ++j) {
                const int row = wcol + j * 16 + lm;
                const int slot = (ks * 4 + quad) ^ (row & 7);
                bf[j] = *(const bfrag*)&sB[row * 64 + slot * 8];
            }
            #pragma unroll
            for (int i = 0; i < FI; ++i)
                #pragma unroll
                for (int j = 0; j < FJ; ++j)
                    acc[i][j] = __builtin_amdgcn_mfma_f32_16x16x32_bf16(
                        af[i], bf[j], acc[i][j], 0, 0, 0);
        }
        __syncthreads();
    }

    // C/D layout: col = lane&15, row = quad*4 + reg
    #pragma unroll
    for (int i = 0; i < FI; ++i)
        #pragma unroll
        for (int j = 0; j < FJ; ++j) {
            const int col = bn + wcol + j * 16 + lm;
            #pragma unroll
            for (int r = 0; r < 4; ++r) {
                const int row = bm + wrow + i * 16 + quad * 4 + r;
                float v = acc[i][j][r];
                if (bias != nullptr) {
                    v += bias[col];
                    v = (v > 20.f) ? v : logf(1.f + expf(v));   // softplus
                    Cb0[(size_t)row * ldc + col] = f2bf(v);
                } else if (split > 0) {
                    if (col < split) Cb0[(size_t)row * split + col] = f2bf(v);
                    else             Cb1[(size_t)row * split + (col - split)] = f2bf(v);
                } else {
                    C[(size_t)row * ldc + col] = v;
                }
            }
        }
}

// ---------------- fused prep: 3 transposes + x cast -------------------------
// blocks [0,4096): W_in^T (1024x4096 -> 4096x1024 bf16)
// blocks [4096,6144): W_out^T (2048x1024 -> 1024x2048 bf16)
// blocks [6144,6272): W_dt^T (64x2048 -> 2048x64 bf16)
// blocks [6272,8320): x cast (2048x1024 f32 -> bf16)
__global__ __launch_bounds__(256) void prep_fused(
    const float* __restrict__ W_in, const float* __restrict__ W_out,
    const float* __restrict__ W_dt, const float* __restrict__ x,
    unsigned short* __restrict__ wbT, unsigned short* __restrict__ wobT,
    unsigned short* __restrict__ wdtT, unsigned short* __restrict__ xb)
{
    __shared__ float tile[32][33];
    const int bx = blockIdx.x;
    const int tid = threadIdx.x;

    const float* in; unsigned short* out; int rows, cols, jt, it;
    if (bx < 4096)      { in = W_in;  out = wbT;  rows = 1024; cols = 4096;
                          jt = bx & 127; it = bx >> 7; }
    else if (bx < 6144) { int t = bx - 4096; in = W_out; out = wobT;
                          rows = 2048; cols = 1024; jt = t & 31; it = t >> 5; }
    else if (bx < 6272) { int t = bx - 6144; in = W_dt;  out = wdtT;
                          rows = 64;   cols = 2048; jt = t & 63; it = t >> 6; }
    else {
        int i = ((bx - 6272) * 256 + tid) * 4;
        float4 v = *(const float4*)&x[i];
        ushort4 o;
        o.x = f2bf(v.x); o.y = f2bf(v.y); o.z = f2bf(v.z); o.w = f2bf(v.w);
        *(ushort4*)&xb[i] = o;
        return;
    }
    const int j0 = jt * 32, i0 = it * 32;
    const int tx = tid & 31, ty = tid >> 5;
    #pragma unroll
    for (int k = 0; k < 4; ++k)
        tile[ty + 8 * k][tx] = in[(size_t)(i0 + ty + 8 * k) * cols + j0 + tx];
    __syncthreads();
    #pragma unroll
    for (int k = 0; k < 4; ++k)
        out[(size_t)(j0 + ty + 8 * k) * rows + i0 + tx] = f2bf(tile[tx][ty + 8 * k]);
}

// ---------------- split-K fp32 GEMM: part[ks] = u_c @ W_x (A is bf16) -------
#define SK_KS 128
__global__ __launch_bounds__(256) void gemm_f32_splitk(
    const unsigned short* __restrict__ A,    // [2048][2048] bf16
    const float* __restrict__ B,
    float* __restrict__ part)                // [16][2048][96]
{
    __shared__ __align__(16) float As[16][64];
    __shared__ __align__(16) float Bs[16][96];

    const int tid = threadIdx.x;
    const int mtile = blockIdx.x >> 4;
    const int kslice = blockIdx.x & 15;
    const int bm = mtile * 64;
    const int kbase = kslice * SK_KS;

    const int am = tid >> 2;
    const int ak = (tid & 3) << 2;

    const int ty = tid >> 4, tx = tid & 15;
    const int rm = ty << 2;
    const int rn = tx * 6;

    float acc[4][6] = {};

    for (int k0 = 0; k0 < SK_KS; k0 += 16) {
        ushort4 av = *(const ushort4*)&A[(size_t)(bm + am) * 2048 + kbase + k0 + ak];
        As[ak + 0][am] = bf2f(av.x);
        As[ak + 1][am] = bf2f(av.y);
        As[ak + 2][am] = bf2f(av.z);
        As[ak + 3][am] = bf2f(av.w);
        for (int i = tid; i < 384; i += 256) {
            int br = i / 24, bc = (i % 24) << 2;
            *(float4*)&Bs[br][bc] = *(const float4*)&B[(size_t)(kbase + k0 + br) * 96 + bc];
        }
        __syncthreads();

        #pragma unroll
        for (int k = 0; k < 16; ++k) {
            float4 a = *(const float4*)&As[k][rm];
            float b[6];
            #pragma unroll
            for (int j = 0; j < 6; ++j) b[j] = Bs[k][rn + j];
            #pragma unroll
            for (int j = 0; j < 6; ++j) {
                acc[0][j] += a.x * b[j];
                acc[1][j] += a.y * b[j];
                acc[2][j] += a.z * b[j];
                acc[3][j] += a.w * b[j];
            }
        }
        __syncthreads();
    }

    float* pout = part + (size_t)kslice * 196608;
    #pragma unroll
    for (int i = 0; i < 4; ++i) {
        float* crow = pout + (size_t)(bm + rm + i) * 96 + rn;
        #pragma unroll
        for (int j = 0; j < 6; ++j)
            crow[j] = acc[i][j];
    }
}

// ---- reduce 16 split-K partials -> xdbl f32; cols<64 also -> bf16 dtl ------
__global__ __launch_bounds__(256) void reduce_splitk(
    const float* __restrict__ part, float* __restrict__ xdbl,
    unsigned short* __restrict__ dtl)        // [2048][64] bf16
{
    int i = (blockIdx.x * 256 + threadIdx.x) * 4;   // < 196608
    float4 acc = {0.f, 0.f, 0.f, 0.f};
    #pragma unroll
    for (int s = 0; s < 16; ++s) {
        float4 v = *(const float4*)&part[(size_t)s * 196608 + i];
        acc.x += v.x; acc.y += v.y; acc.z += v.z; acc.w += v.w;
    }
    *(float4*)&xdbl[i] = acc;
    int row = i / 96, col = i % 96;                 // col in {0,4,...,92}
    if (col < 64) {
        ushort4 o;
        o.x = f2bf(acc.x); o.y = f2bf(acc.y);
        o.z = f2bf(acc.z); o.w = f2bf(acc.w);
        *(ushort4*)&dtl[(size_t)row * 64 + col] = o;
    }
}

// ---------------- depthwise causal conv(4) + bias + SiLU (bf16 in/out) ------
__global__ __launch_bounds__(256) void conv_silu_kernel(
    const unsigned short* __restrict__ ub, const float* __restrict__ cw,
    const float* __restrict__ cb, unsigned short* __restrict__ uc)
{
    int idx = blockIdx.x * 256 + threadIdx.x;
    int d = idx & 2047;
    int r = idx >> 11;
    int l = r & 1023;

    float4 w4 = *(const float4*)(cw + 4 * d);
    float w[4] = { w4.x, w4.y, w4.z, w4.w };
    float acc = cb[d];
    const unsigned short* up = ub + (size_t)r * 2048 + d;
    if (l >= 3) {
        acc += w[0] * bf2f(up[-3 * 2048]) + w[1] * bf2f(up[-2 * 2048])
             + w[2] * bf2f(up[-1 * 2048]) + w[3] * bf2f(up[0]);
    } else {
        #pragma unroll
        for (int j = 0; j < 4; ++j) {
            int lj = l - 3 + j;
            if (lj >= 0) acc += w[j] * bf2f(up[(j - 3) * 2048]);
        }
    }
    float sig = 1.f / (1.f + expf(-acc));
    uc[idx] = f2bf(acc * sig);
}

// ---------------------------------------------------------------------------
// Register-state chunk-parallel scan (thread per (b,d,chunk), h[16] in VGPRs).
// ---------------------------------------------------------------------------
__global__ __launch_bounds__(256) void scan_pass1(
    const unsigned short* __restrict__ uc,
    const unsigned short* __restrict__ dtb,
    const float* __restrict__ xdbl,
    const float* __restrict__ A_log,
    float* __restrict__ Hend,         // [2][CF][2048][16]
    float* __restrict__ Sdt)          // [2][CF][2048]
{
    __shared__ float sB[CLEN][16];
    const int tid = threadIdx.x;
    const int bx  = blockIdx.x;
    const int c   = bx & (CF - 1);
    const int g   = (bx >> 5) & 7;
    const int b   = bx >> 8;
    const int d   = g * 256 + tid;
    const size_t rowbase = (size_t)b * 1024 + c * CLEN;

    for (int i = tid; i < CLEN * 16; i += 256) {
        int tt = i >> 4, nn = i & 15;
        sB[tt][nn] = xdbl[(rowbase + tt) * 96 + 64 + nn];
    }

    float A2[16];
    {
        float al[16];
        #pragma unroll
        for (int q = 0; q < 4; ++q)
            *(float4*)&al[4 * q] = *(const float4*)&A_log[(size_t)d * 16 + 4 * q];
        #pragma unroll
        for (int n = 0; n < 16; ++n) A2[n] = -expf(al[n]) * 1.44269504f;
    }
    __syncthreads();

    float h[16];
    #pragma unroll
    for (int n = 0; n < 16; ++n) h[n] = 0.f;
    float sdt = 0.f;

    #pragma unroll 4
    for (int t = 0; t < CLEN; ++t) {
        size_t r = rowbase + t;
        float dtv = bf2f(dtb[r * 2048 + d]);
        float uv  = bf2f(uc [r * 2048 + d]);
        sdt += dtv;
        float dtu = dtv * uv;
        float bl[16];
        #pragma unroll
        for (int q = 0; q < 4; ++q)
            *(float4*)&bl[4 * q] = *(const float4*)&sB[t][4 * q];
        #pragma unroll
        for (int n = 0; n < 16; ++n)
            h[n] = exp2f(dtv * A2[n]) * h[n] + dtu * bl[n];
    }

    size_t base = ((size_t)(b * CF + c) * 2048 + d) * 16;
    #pragma unroll
    for (int q = 0; q < 4; ++q)
        *(float4*)&Hend[base + 4 * q] = *(float4*)&h[4 * q];
    Sdt[(size_t)(b * CF + c) * 2048 + d] = sdt;
}

__global__ __launch_bounds__(256) void scan_pass2(
    const float* __restrict__ Hend, const float* __restrict__ Sdt,
    const float* __restrict__ A_log, float* __restrict__ Hin)
{
    int gid = blockIdx.x * 256 + threadIdx.x;   // 0..65535
    int b = gid >> 15;
    int rest = gid & 32767;                     // d*16+n
    int d = rest >> 4;
    float A2 = -expf(A_log[rest]) * 1.44269504f;
    float H = 0.f;
    #pragma unroll
    for (int c = 0; c < CF; ++c) {
        size_t sidx = (size_t)(b * CF + c) * 2048 + d;
        size_t idx  = ((size_t)(b * CF + c) << 15) + rest;
        Hin[idx] = H;
        H = exp2f(A2 * Sdt[sidx]) * H + Hend[idx];
    }
}

__global__ __launch_bounds__(256) void scan_pass3(
    const unsigned short* __restrict__ uc,
    const unsigned short* __restrict__ dtb,
    const unsigned short* __restrict__ zb,  // [2048][2048] bf16
    const float* __restrict__ xdbl,
    const float* __restrict__ A_log,
    const float* __restrict__ Dvec,
    const float* __restrict__ Hin,
    unsigned short* __restrict__ yb)
{
    __shared__ float sBC[CLEN][32];
    const int tid = threadIdx.x;
    const int bx  = blockIdx.x;
    const int c   = bx & (CF - 1);
    const int g   = (bx >> 5) & 7;
    const int b   = bx >> 8;
    const int d   = g * 256 + tid;
    const size_t rowbase = (size_t)b * 1024 + c * CLEN;

    for (int i = tid; i < CLEN * 32; i += 256) {
        int tt = i >> 5, j = i & 31;
        sBC[tt][j] = xdbl[(rowbase + tt) * 96 + 64 + j];
    }

    float A2[16];
    {
        float al[16];
        #pragma unroll
        for (int q = 0; q < 4; ++q)
            *(float4*)&al[4 * q] = *(const float4*)&A_log[(size_t)d * 16 + 4 * q];
        #pragma unroll
        for (int n = 0; n < 16; ++n) A2[n] = -expf(al[n]) * 1.44269504f;
    }
    const float Dd = Dvec[d];

    float h[16];
    {
        size_t base = ((size_t)(b * CF + c) * 2048 + d) * 16;
        #pragma unroll
        for (int q = 0; q < 4; ++q)
            *(float4*)&h[4 * q] = *(const float4*)&Hin[base + 4 * q];
    }
    __syncthreads();

    #pragma unroll 2
    for (int t = 0; t < CLEN; ++t) {
        size_t r = rowbase + t;
        float dtv = bf2f(dtb[r * 2048 + d]);
        float uv  = bf2f(uc [r * 2048 + d]);
        float zv  = bf2f(zb [r * 2048 + d]);
        float dtu = dtv * uv;
        float bl[16], cl[16];
        #pragma unroll
        for (int q = 0; q < 4; ++q) {
            *(float4*)&bl[4 * q] = *(const float4*)&sBC[t][4 * q];
            *(float4*)&cl[4 * q] = *(const float4*)&sBC[t][16 + 4 * q];
        }
        float acc = uv * Dd;
        #pragma unroll
        for (int n = 0; n < 16; ++n) {
            h[n] = exp2f(dtv * A2[n]) * h[n] + dtu * bl[n];
            acc += h[n] * cl[n];
        }
        float yv = acc * zv / (1.f + expf(-zv));
        yb[r * 2048 + d] = f2bf(yv);
    }
}

extern "C" void kernel_launch(void* const* d_in, const int* in_sizes, int n_in,
                              void* d_out, int out_size, void* d_ws, size_t ws_size,
                              hipStream_t stream)
{
    const float* x      = (const float*)d_in[0];
    const float* W_in   = (const float*)d_in[1];
    const float* conv_w = (const float*)d_in[2];
    const float* conv_b = (const float*)d_in[3];
    const float* W_x    = (const float*)d_in[4];
    const float* W_dt   = (const float*)d_in[5];
    const float* b_dt   = (const float*)d_in[6];
    const float* A_log  = (const float*)d_in[7];
    const float* Dv     = (const float*)d_in[8];
    const float* W_out  = (const float*)d_in[9];
    float* out = (float*)d_out;

    float* ws = (float*)d_ws;
    unsigned short* ub  = (unsigned short*)ws;        // [2048][2048] bf16 (u_pre)
    unsigned short* dtb = ub;                         // ALIAS: dt overwrites u_pre
                                                      //   (dead after conv)
    unsigned short* uc  = ub + 4194304;               // [2048][2048] bf16
    float* xdbl = ws + 4194304;                       // [2048][96] f32
    unsigned short* dtl = (unsigned short*)(xdbl + 196608);  // [2048][64] bf16
    float* Hend = xdbl + 196608 + 65536;              // 2097152 f32
    float* Hin  = Hend + 2097152;                     // 2097152 f32
    float* Sdt  = Hin + 2097152;                      // 131072 f32
    float* part = Hend;                               // ALIAS: [16][2048][96]
                                                      //   (dead before pass1/2)
    unsigned short* zb   = (unsigned short*)(Sdt + 131072);  // [2048][2048] bf16
    unsigned short* xb   = zb + 4194304;              // [2048][1024] bf16
    unsigned short* wbT  = xb + 2097152;              // [4096][1024] bf16
    unsigned short* wobT = wbT + 4194304;             // [1024][2048] bf16
    unsigned short* wdtT = wobT + 2097152;            // [2048][64] bf16
    unsigned short* yb   = wbT;                       // aliases wbT (dead after GEMM1)

    dim3 blk(256);

    // 0. fused prep: W_in^T, W_out^T, W_dt^T, x cast
    prep_fused<<<8320, blk, 0, stream>>>(W_in, W_out, W_dt, x,
                                         wbT, wobT, wdtT, xb);

    // 1. xz = x @ W_in   (bf16 MFMA, 128x64 tile -> 1024 blocks; u/z bf16)
    gemm_bf16_v2<128, 64><<<dim3(64, 16), blk, 0, stream>>>(
        xb, wbT, nullptr, ub, zb, 1024, 1024, 1024, 2048, 2048, nullptr);

    // 2. u_c = silu(conv(u) + cb)   (bf16 in/out)
    conv_silu_kernel<<<(2048 * 2048) / 256, blk, 0, stream>>>(ub, conv_w, conv_b, uc);

    // 3. x_dbl = u_c @ W_x   (split-K, partials + reduce; emits bf16 dtl)
    gemm_f32_splitk<<<512, blk, 0, stream>>>(uc, W_x, part);
    reduce_splitk<<<192, blk, 0, stream>>>(part, xdbl, dtl);

    // 4. dt = softplus(dtl @ W_dt + b_dt)   (bf16 MFMA, K=64, softplus epi)
    gemm_bf16_v2<128, 128><<<dim3(16, 16), blk, 0, stream>>>(
        dtl, wdtT, nullptr, dtb, nullptr, 64, 64, 64, 2048, 0, b_dt);

    // 5. register-state chunk scan
    scan_pass1<<<512, blk, 0, stream>>>(uc, dtb, xdbl, A_log, Hend, Sdt);
    scan_pass2<<<256, blk, 0, stream>>>(Hend, Sdt, A_log, Hin);
    scan_pass3<<<512, blk, 0, stream>>>(uc, dtb, zb, xdbl, A_log, Dv, Hin, yb);

    // 6. out = y @ W_out   (bf16 MFMA, 64x64 tile -> 512 blocks)
    gemm_bf16_v2<64, 64><<<dim3(16, 32), blk, 0, stream>>>(
        yb, wobT, out, nullptr, nullptr, 2048, 2048, 2048, 1024, 0, nullptr);
}

// Round 11
// 269.449 us; speedup vs baseline: 1.0233x; 1.0233x over previous
//
#include <hip/hip_runtime.h>
#include <hip/hip_bf16.h>

// ---------------------------------------------------------------------------
// Mamba block forward. Round 11: LDS-staged scan passes (kill the exposed
// global-load latency on the serial h-chain), GEMM1 back to 128x128.
// B=2 L=1024 DM=1024 DI=2048 DS=16 DTR=64
// ---------------------------------------------------------------------------

typedef __attribute__((ext_vector_type(8))) short bfrag;
typedef __attribute__((ext_vector_type(4))) float f32x4;

#define CF   32   // scan time-chunks
#define CLEN 32   // steps per chunk (CF*CLEN = 1024)

__device__ __forceinline__ unsigned short f2bf(float f) {
    unsigned int u = __float_as_uint(f);
    u += 0x7FFF + ((u >> 16) & 1);          // round-to-nearest-even
    return (unsigned short)(u >> 16);
}
__device__ __forceinline__ float bf2f(unsigned short s) {
    return __uint_as_float((unsigned int)s << 16);
}

__device__ __forceinline__ void async_copy16(const unsigned short* g,
                                             unsigned short* l) {
    __builtin_amdgcn_global_load_lds(
        (const __attribute__((address_space(1))) void*)g,
        (__attribute__((address_space(3))) void*)l, 16, 0, 0);
}

// ---------------- bf16 MFMA GEMM v2: C[M][N] = A[M][K] * BT[N][K]^T ---------
// Tile MT x NT, BK=64, 4 waves (2x2), wave does (MT/2)x(NT/2).
// XOR-swizzled unpadded LDS; global_load_lds width-16 staging.
// Epilogue: bias!=null -> softplus(v+bias[col]) -> bf16 Cb0 (ld=ldc)
//           split>0    -> col<split: bf16 Cb0 ; else bf16 Cb1 (ld=split)
//           else       -> fp32 C (ld=ldc)
template<int MT, int NT>
__global__ __launch_bounds__(256) void gemm_bf16_v2(
    const unsigned short* __restrict__ A,   // [M][K] bf16
    const unsigned short* __restrict__ BT,  // [N][K] bf16
    float* __restrict__ C,
    unsigned short* __restrict__ Cb0,
    unsigned short* __restrict__ Cb1,
    int K, int lda, int ldb, int ldc, int split,
    const float* __restrict__ bias)
{
    constexpr int FI  = MT / 32;
    constexpr int FJ  = NT / 32;
    constexpr int ACH = MT / 32;            // A 1KB-chunks per wave
    constexpr int BCH = NT / 32;
    __shared__ __align__(16) unsigned short sA[MT * 64];
    __shared__ __align__(16) unsigned short sB[NT * 64];

    const int tid  = threadIdx.x;
    const int wave = tid >> 6, lane = tid & 63;
    const int lm   = lane & 15;
    const int quad = lane >> 4;
    const int wrow = (wave >> 1) * (MT / 2);
    const int wcol = (wave & 1) * (NT / 2);
    const int bm = blockIdx.y * MT, bn = blockIdx.x * NT;

    const int lrow = lane >> 3;             // 0..7 (row within 8-row chunk)
    const int lkb  = (lane & 7) ^ lrow;     // swizzled k-block to fetch

    f32x4 acc[FI][FJ];
    #pragma unroll
    for (int i = 0; i < FI; ++i)
        #pragma unroll
        for (int j = 0; j < FJ; ++j) {
            acc[i][j][0] = 0.f; acc[i][j][1] = 0.f;
            acc[i][j][2] = 0.f; acc[i][j][3] = 0.f;
        }

    for (int k0 = 0; k0 < K; k0 += 64) {
        #pragma unroll
        for (int c = 0; c < ACH; ++c) {
            const int chunk = wave * ACH + c;
            const int row = chunk * 8 + lrow;
            async_copy16(&A[(size_t)(bm + row) * lda + k0 + lkb * 8],
                         &sA[chunk * 512 + lane * 8]);
        }
        #pragma unroll
        for (int c = 0; c < BCH; ++c) {
            const int chunk = wave * BCH + c;
            const int row = chunk * 8 + lrow;
            async_copy16(&BT[(size_t)(bn + row) * ldb + k0 + lkb * 8],
                         &sB[chunk * 512 + lane * 8]);
        }
        __syncthreads();

        #pragma unroll
        for (int ks = 0; ks < 2; ++ks) {
            bfrag af[FI], bf[FJ];
            #pragma unroll
            for (int i = 0; i < FI; ++i) {
                const int row = wrow + i * 16 + lm;
                const int slot = (ks * 4 + quad) ^ (row & 7);
                af[i] = *(const bfrag*)&sA[row * 64 + slot * 8];
            }
            #pragma unroll
            for (int j = 0; j < FJ; ++j) {
                const int row = wcol + j * 16 + lm;
                const int slot = (ks * 4 + quad) ^ (row & 7);
                bf[j] = *(const bfrag*)&sB[row * 64 + slot * 8];
            }
            #pragma unroll
            for (int i = 0; i < FI; ++i)
                #pragma unroll
                for (int j = 0; j < FJ; ++j)
                    acc[i][j] = __builtin_amdgcn_mfma_f32_16x16x32_bf16(
                        af[i], bf[j], acc[i][j], 0, 0, 0);
        }
        __syncthreads();
    }

    // C/D layout: col = lane&15, row = quad*4 + reg
    #pragma unroll
    for (int i = 0; i < FI; ++i)
        #pragma unroll
        for (int j = 0; j < FJ; ++j) {
            const int col = bn + wcol + j * 16 + lm;
            #pragma unroll
            for (int r = 0; r < 4; ++r) {
                const int row = bm + wrow + i * 16 + quad * 4 + r;
                float v = acc[i][j][r];
                if (bias != nullptr) {
                    v += bias[col];
                    v = (v > 20.f) ? v : logf(1.f + expf(v));   // softplus
                    Cb0[(size_t)row * ldc + col] = f2bf(v);
                } else if (split > 0) {
                    if (col < split) Cb0[(size_t)row * split + col] = f2bf(v);
                    else             Cb1[(size_t)row * split + (col - split)] = f2bf(v);
                } else {
                    C[(size_t)row * ldc + col] = v;
                }
            }
        }
}

// ---------------- fused prep: 3 transposes + x cast -------------------------
__global__ __launch_bounds__(256) void prep_fused(
    const float* __restrict__ W_in, const float* __restrict__ W_out,
    const float* __restrict__ W_dt, const float* __restrict__ x,
    unsigned short* __restrict__ wbT, unsigned short* __restrict__ wobT,
    unsigned short* __restrict__ wdtT, unsigned short* __restrict__ xb)
{
    __shared__ float tile[32][33];
    const int bx = blockIdx.x;
    const int tid = threadIdx.x;

    const float* in; unsigned short* out; int rows, cols, jt, it;
    if (bx < 4096)      { in = W_in;  out = wbT;  rows = 1024; cols = 4096;
                          jt = bx & 127; it = bx >> 7; }
    else if (bx < 6144) { int t = bx - 4096; in = W_out; out = wobT;
                          rows = 2048; cols = 1024; jt = t & 31; it = t >> 5; }
    else if (bx < 6272) { int t = bx - 6144; in = W_dt;  out = wdtT;
                          rows = 64;   cols = 2048; jt = t & 63; it = t >> 6; }
    else {
        int i = ((bx - 6272) * 256 + tid) * 4;
        float4 v = *(const float4*)&x[i];
        ushort4 o;
        o.x = f2bf(v.x); o.y = f2bf(v.y); o.z = f2bf(v.z); o.w = f2bf(v.w);
        *(ushort4*)&xb[i] = o;
        return;
    }
    const int j0 = jt * 32, i0 = it * 32;
    const int tx = tid & 31, ty = tid >> 5;
    #pragma unroll
    for (int k = 0; k < 4; ++k)
        tile[ty + 8 * k][tx] = in[(size_t)(i0 + ty + 8 * k) * cols + j0 + tx];
    __syncthreads();
    #pragma unroll
    for (int k = 0; k < 4; ++k)
        out[(size_t)(j0 + ty + 8 * k) * rows + i0 + tx] = f2bf(tile[tx][ty + 8 * k]);
}

// ---------------- split-K fp32 GEMM: part[ks] = u_c @ W_x (A is bf16) -------
#define SK_KS 128
__global__ __launch_bounds__(256) void gemm_f32_splitk(
    const unsigned short* __restrict__ A,    // [2048][2048] bf16
    const float* __restrict__ B,
    float* __restrict__ part)                // [16][2048][96]
{
    __shared__ __align__(16) float As[16][64];
    __shared__ __align__(16) float Bs[16][96];

    const int tid = threadIdx.x;
    const int mtile = blockIdx.x >> 4;
    const int kslice = blockIdx.x & 15;
    const int bm = mtile * 64;
    const int kbase = kslice * SK_KS;

    const int am = tid >> 2;
    const int ak = (tid & 3) << 2;

    const int ty = tid >> 4, tx = tid & 15;
    const int rm = ty << 2;
    const int rn = tx * 6;

    float acc[4][6] = {};

    for (int k0 = 0; k0 < SK_KS; k0 += 16) {
        ushort4 av = *(const ushort4*)&A[(size_t)(bm + am) * 2048 + kbase + k0 + ak];
        As[ak + 0][am] = bf2f(av.x);
        As[ak + 1][am] = bf2f(av.y);
        As[ak + 2][am] = bf2f(av.z);
        As[ak + 3][am] = bf2f(av.w);
        for (int i = tid; i < 384; i += 256) {
            int br = i / 24, bc = (i % 24) << 2;
            *(float4*)&Bs[br][bc] = *(const float4*)&B[(size_t)(kbase + k0 + br) * 96 + bc];
        }
        __syncthreads();

        #pragma unroll
        for (int k = 0; k < 16; ++k) {
            float4 a = *(const float4*)&As[k][rm];
            float b[6];
            #pragma unroll
            for (int j = 0; j < 6; ++j) b[j] = Bs[k][rn + j];
            #pragma unroll
            for (int j = 0; j < 6; ++j) {
                acc[0][j] += a.x * b[j];
                acc[1][j] += a.y * b[j];
                acc[2][j] += a.z * b[j];
                acc[3][j] += a.w * b[j];
            }
        }
        __syncthreads();
    }

    float* pout = part + (size_t)kslice * 196608;
    #pragma unroll
    for (int i = 0; i < 4; ++i) {
        float* crow = pout + (size_t)(bm + rm + i) * 96 + rn;
        #pragma unroll
        for (int j = 0; j < 6; ++j)
            crow[j] = acc[i][j];
    }
}

// ---- reduce 16 split-K partials -> xdbl f32; cols<64 also -> bf16 dtl ------
__global__ __launch_bounds__(256) void reduce_splitk(
    const float* __restrict__ part, float* __restrict__ xdbl,
    unsigned short* __restrict__ dtl)        // [2048][64] bf16
{
    int i = (blockIdx.x * 256 + threadIdx.x) * 4;   // < 196608
    float4 acc = {0.f, 0.f, 0.f, 0.f};
    #pragma unroll
    for (int s = 0; s < 16; ++s) {
        float4 v = *(const float4*)&part[(size_t)s * 196608 + i];
        acc.x += v.x; acc.y += v.y; acc.z += v.z; acc.w += v.w;
    }
    *(float4*)&xdbl[i] = acc;
    int row = i / 96, col = i % 96;
    if (col < 64) {
        ushort4 o;
        o.x = f2bf(acc.x); o.y = f2bf(acc.y);
        o.z = f2bf(acc.z); o.w = f2bf(acc.w);
        *(ushort4*)&dtl[(size_t)row * 64 + col] = o;
    }
}

// ---------------- depthwise causal conv(4) + bias + SiLU (bf16 in/out) ------
__global__ __launch_bounds__(256) void conv_silu_kernel(
    const unsigned short* __restrict__ ub, const float* __restrict__ cw,
    const float* __restrict__ cb, unsigned short* __restrict__ uc)
{
    int idx = blockIdx.x * 256 + threadIdx.x;
    int d = idx & 2047;
    int r = idx >> 11;
    int l = r & 1023;

    float4 w4 = *(const float4*)(cw + 4 * d);
    float w[4] = { w4.x, w4.y, w4.z, w4.w };
    float acc = cb[d];
    const unsigned short* up = ub + (size_t)r * 2048 + d;
    if (l >= 3) {
        acc += w[0] * bf2f(up[-3 * 2048]) + w[1] * bf2f(up[-2 * 2048])
             + w[2] * bf2f(up[-1 * 2048]) + w[3] * bf2f(up[0]);
    } else {
        #pragma unroll
        for (int j = 0; j < 4; ++j) {
            int lj = l - 3 + j;
            if (lj >= 0) acc += w[j] * bf2f(up[(j - 3) * 2048]);
        }
    }
    float sig = 1.f / (1.f + expf(-acc));
    uc[idx] = f2bf(acc * sig);
}

// ---------------------------------------------------------------------------
// Register-state chunk-parallel scan, LDS-staged inputs.
// Thread = one (batch, channel, chunk); h[16] in VGPRs. Block = 256 channels.
// Grid = 2 x 8 ch-groups x CF = 512 blocks.
// ---------------------------------------------------------------------------
__global__ __launch_bounds__(256) void scan_pass1(
    const unsigned short* __restrict__ uc,
    const unsigned short* __restrict__ dtb,
    const float* __restrict__ xdbl,
    const float* __restrict__ A_log,
    float* __restrict__ Hend,         // [2][CF][2048][16]
    float* __restrict__ Sdt)          // [2][CF][2048]
{
    __shared__ __align__(16) unsigned short su [CLEN][256];
    __shared__ __align__(16) unsigned short sdt[CLEN][256];
    __shared__ float sB[CLEN][16];
    const int tid = threadIdx.x;
    const int bx  = blockIdx.x;
    const int c   = bx & (CF - 1);
    const int g   = (bx >> 5) & 7;
    const int b   = bx >> 8;
    const int dbase = g * 256;
    const int d   = dbase + tid;
    const size_t rowbase = (size_t)b * 1024 + c * CLEN;

    // ---- cooperative staging: u, dt (16KB each, float4-coalesced) ----
    #pragma unroll
    for (int q = 0; q < 4; ++q) {
        int i = q * 256 + tid;              // 1024 chunks of 8 shorts
        int row = i >> 5, off = (i & 31) * 8;
        size_t gaddr = (rowbase + row) * 2048 + dbase + off;
        *(float4*)&su [row][off] = *(const float4*)&uc [gaddr];
        *(float4*)&sdt[row][off] = *(const float4*)&dtb[gaddr];
    }
    for (int i = tid; i < CLEN * 16; i += 256) {
        int tt = i >> 4, nn = i & 15;
        sB[tt][nn] = xdbl[(rowbase + tt) * 96 + 64 + nn];
    }

    float A2[16];
    {
        float al[16];
        #pragma unroll
        for (int q = 0; q < 4; ++q)
            *(float4*)&al[4 * q] = *(const float4*)&A_log[(size_t)d * 16 + 4 * q];
        #pragma unroll
        for (int n = 0; n < 16; ++n) A2[n] = -expf(al[n]) * 1.44269504f;
    }
    __syncthreads();

    float h[16];
    #pragma unroll
    for (int n = 0; n < 16; ++n) h[n] = 0.f;
    float sdtv = 0.f;

    #pragma unroll 4
    for (int t = 0; t < CLEN; ++t) {
        float dtv = bf2f(sdt[t][tid]);
        float uv  = bf2f(su [t][tid]);
        sdtv += dtv;
        float dtu = dtv * uv;
        float bl[16];
        #pragma unroll
        for (int q = 0; q < 4; ++q)
            *(float4*)&bl[4 * q] = *(const float4*)&sB[t][4 * q];
        #pragma unroll
        for (int n = 0; n < 16; ++n)
            h[n] = exp2f(dtv * A2[n]) * h[n] + dtu * bl[n];
    }

    size_t base = ((size_t)(b * CF + c) * 2048 + d) * 16;
    #pragma unroll
    for (int q = 0; q < 4; ++q)
        *(float4*)&Hend[base + 4 * q] = *(float4*)&h[4 * q];
    Sdt[(size_t)(b * CF + c) * 2048 + d] = sdtv;
}

__global__ __launch_bounds__(256) void scan_pass2(
    const float* __restrict__ Hend, const float* __restrict__ Sdt,
    const float* __restrict__ A_log, float* __restrict__ Hin)
{
    int gid = blockIdx.x * 256 + threadIdx.x;   // 0..65535
    int b = gid >> 15;
    int rest = gid & 32767;                     // d*16+n
    int d = rest >> 4;
    float A2 = -expf(A_log[rest]) * 1.44269504f;
    float H = 0.f;
    #pragma unroll
    for (int c = 0; c < CF; ++c) {
        size_t sidx = (size_t)(b * CF + c) * 2048 + d;
        size_t idx  = ((size_t)(b * CF + c) << 15) + rest;
        Hin[idx] = H;
        H = exp2f(A2 * Sdt[sidx]) * H + Hend[idx];
    }
}

__global__ __launch_bounds__(256) void scan_pass3(
    const unsigned short* __restrict__ uc,
    const unsigned short* __restrict__ dtb,
    const unsigned short* __restrict__ zb,  // [2048][2048] bf16
    const float* __restrict__ xdbl,
    const float* __restrict__ A_log,
    const float* __restrict__ Dvec,
    const float* __restrict__ Hin,
    unsigned short* __restrict__ yb)
{
    __shared__ __align__(16) unsigned short su [CLEN][256];
    __shared__ __align__(16) unsigned short sdt[CLEN][256];
    __shared__ __align__(16) unsigned short sz [CLEN][256];  // z in, y out
    __shared__ float sBC[CLEN][32];
    const int tid = threadIdx.x;
    const int bx  = blockIdx.x;
    const int c   = bx & (CF - 1);
    const int g   = (bx >> 5) & 7;
    const int b   = bx >> 8;
    const int dbase = g * 256;
    const int d   = dbase + tid;
    const size_t rowbase = (size_t)b * 1024 + c * CLEN;

    #pragma unroll
    for (int q = 0; q < 4; ++q) {
        int i = q * 256 + tid;
        int row = i >> 5, off = (i & 31) * 8;
        size_t gaddr = (rowbase + row) * 2048 + dbase + off;
        *(float4*)&su [row][off] = *(const float4*)&uc [gaddr];
        *(float4*)&sdt[row][off] = *(const float4*)&dtb[gaddr];
        *(float4*)&sz [row][off] = *(const float4*)&zb [gaddr];
    }
    for (int i = tid; i < CLEN * 32; i += 256) {
        int tt = i >> 5, j = i & 31;
        sBC[tt][j] = xdbl[(rowbase + tt) * 96 + 64 + j];
    }

    float A2[16];
    {
        float al[16];
        #pragma unroll
        for (int q = 0; q < 4; ++q)
            *(float4*)&al[4 * q] = *(const float4*)&A_log[(size_t)d * 16 + 4 * q];
        #pragma unroll
        for (int n = 0; n < 16; ++n) A2[n] = -expf(al[n]) * 1.44269504f;
    }
    const float Dd = Dvec[d];

    float h[16];
    {
        size_t base = ((size_t)(b * CF + c) * 2048 + d) * 16;
        #pragma unroll
        for (int q = 0; q < 4; ++q)
            *(float4*)&h[4 * q] = *(const float4*)&Hin[base + 4 * q];
    }
    __syncthreads();

    #pragma unroll 4
    for (int t = 0; t < CLEN; ++t) {
        float dtv = bf2f(sdt[t][tid]);
        float uv  = bf2f(su [t][tid]);
        float zv  = bf2f(sz [t][tid]);
        float dtu = dtv * uv;
        float bl[16], cl[16];
        #pragma unroll
        for (int q = 0; q < 4; ++q) {
            *(float4*)&bl[4 * q] = *(const float4*)&sBC[t][4 * q];
            *(float4*)&cl[4 * q] = *(const float4*)&sBC[t][16 + 4 * q];
        }
        float acc = uv * Dd;
        #pragma unroll
        for (int n = 0; n < 16; ++n) {
            h[n] = exp2f(dtv * A2[n]) * h[n] + dtu * bl[n];
            acc += h[n] * cl[n];
        }
        float yv = acc * zv / (1.f + expf(-zv));
        sz[t][tid] = f2bf(yv);              // reuse z slot (read-once, same thread)
    }
    __syncthreads();

    // ---- vectorized writeback of y chunk ----
    #pragma unroll
    for (int q = 0; q < 4; ++q) {
        int i = q * 256 + tid;
        int row = i >> 5, off = (i & 31) * 8;
        size_t gaddr = (rowbase + row) * 2048 + dbase + off;
        *(float4*)&yb[gaddr] = *(const float4*)&sz[row][off];
    }
}

extern "C" void kernel_launch(void* const* d_in, const int* in_sizes, int n_in,
                              void* d_out, int out_size, void* d_ws, size_t ws_size,
                              hipStream_t stream)
{
    const float* x      = (const float*)d_in[0];
    const float* W_in   = (const float*)d_in[1];
    const float* conv_w = (const float*)d_in[2];
    const float* conv_b = (const float*)d_in[3];
    const float* W_x    = (const float*)d_in[4];
    const float* W_dt   = (const float*)d_in[5];
    const float* b_dt   = (const float*)d_in[6];
    const float* A_log  = (const float*)d_in[7];
    const float* Dv     = (const float*)d_in[8];
    const float* W_out  = (const float*)d_in[9];
    float* out = (float*)d_out;

    float* ws = (float*)d_ws;
    unsigned short* ub  = (unsigned short*)ws;        // [2048][2048] bf16 (u_pre)
    unsigned short* dtb = ub;                         // ALIAS: dt overwrites u_pre
    unsigned short* uc  = ub + 4194304;               // [2048][2048] bf16
    float* xdbl = ws + 4194304;                       // [2048][96] f32
    unsigned short* dtl = (unsigned short*)(xdbl + 196608);  // [2048][64] bf16
    float* Hend = xdbl + 196608 + 65536;              // 2097152 f32
    float* Hin  = Hend + 2097152;                     // 2097152 f32
    float* Sdt  = Hin + 2097152;                      // 131072 f32
    float* part = Hend;                               // ALIAS: [16][2048][96]
    unsigned short* zb   = (unsigned short*)(Sdt + 131072);  // [2048][2048] bf16
    unsigned short* xb   = zb + 4194304;              // [2048][1024] bf16
    unsigned short* wbT  = xb + 2097152;              // [4096][1024] bf16
    unsigned short* wobT = wbT + 4194304;             // [1024][2048] bf16
    unsigned short* wdtT = wobT + 2097152;            // [2048][64] bf16
    unsigned short* yb   = wbT;                       // aliases wbT

    dim3 blk(256);

    // 0. fused prep
    prep_fused<<<8320, blk, 0, stream>>>(W_in, W_out, W_dt, x,
                                         wbT, wobT, wdtT, xb);

    // 1. xz = x @ W_in   (bf16 MFMA, 128x128 -> 512 blocks; u/z bf16)
    gemm_bf16_v2<128, 128><<<dim3(32, 16), blk, 0, stream>>>(
        xb, wbT, nullptr, ub, zb, 1024, 1024, 1024, 2048, 2048, nullptr);

    // 2. u_c = silu(conv(u) + cb)
    conv_silu_kernel<<<(2048 * 2048) / 256, blk, 0, stream>>>(ub, conv_w, conv_b, uc);

    // 3. x_dbl = u_c @ W_x   (split-K + reduce; emits bf16 dtl)
    gemm_f32_splitk<<<512, blk, 0, stream>>>(uc, W_x, part);
    reduce_splitk<<<192, blk, 0, stream>>>(part, xdbl, dtl);

    // 4. dt = softplus(dtl @ W_dt + b_dt)   (bf16 MFMA, K=64)
    gemm_bf16_v2<128, 128><<<dim3(16, 16), blk, 0, stream>>>(
        dtl, wdtT, nullptr, dtb, nullptr, 64, 64, 64, 2048, 0, b_dt);

    // 5. register-state chunk scan (LDS-staged)
    scan_pass1<<<512, blk, 0, stream>>>(uc, dtb, xdbl, A_log, Hend, Sdt);
    scan_pass2<<<256, blk, 0, stream>>>(Hend, Sdt, A_log, Hin);
    scan_pass3<<<512, blk, 0, stream>>>(uc, dtb, zb, xdbl, A_log, Dv, Hin, yb);

    // 6. out = y @ W_out   (bf16 MFMA, 64x64 -> 512 blocks)
    gemm_bf16_v2<64, 64><<<dim3(16, 32), blk, 0, stream>>>(
        yb, wobT, out, nullptr, nullptr, 2048, 2048, 2048, 1024, 0, nullptr);
}

// Round 12
// 259.612 us; speedup vs baseline: 1.0621x; 1.0379x over previous
//
#include <hip/hip_runtime.h>
#include <hip/hip_bf16.h>

// ---------------------------------------------------------------------------
// Mamba block forward. Round 12: dt-GEMM fused into scan passes as in-block
// MFMA (dtb buffer eliminated), conv vectorized x8 channels.
// B=2 L=1024 DM=1024 DI=2048 DS=16 DTR=64
// ---------------------------------------------------------------------------

typedef __attribute__((ext_vector_type(8))) short bfrag;
typedef __attribute__((ext_vector_type(4))) float f32x4;

#define CF   32   // scan time-chunks
#define CLEN 32   // steps per chunk (CF*CLEN = 1024)

__device__ __forceinline__ unsigned short f2bf(float f) {
    unsigned int u = __float_as_uint(f);
    u += 0x7FFF + ((u >> 16) & 1);          // round-to-nearest-even
    return (unsigned short)(u >> 16);
}
__device__ __forceinline__ float bf2f(unsigned short s) {
    return __uint_as_float((unsigned int)s << 16);
}

__device__ __forceinline__ void async_copy16(const unsigned short* g,
                                             unsigned short* l) {
    __builtin_amdgcn_global_load_lds(
        (const __attribute__((address_space(1))) void*)g,
        (__attribute__((address_space(3))) void*)l, 16, 0, 0);
}

// ---------------- bf16 MFMA GEMM v2: C[M][N] = A[M][K] * BT[N][K]^T ---------
template<int MT, int NT>
__global__ __launch_bounds__(256) void gemm_bf16_v2(
    const unsigned short* __restrict__ A,   // [M][K] bf16
    const unsigned short* __restrict__ BT,  // [N][K] bf16
    float* __restrict__ C,
    unsigned short* __restrict__ Cb0,
    unsigned short* __restrict__ Cb1,
    int K, int lda, int ldb, int ldc, int split)
{
    constexpr int FI  = MT / 32;
    constexpr int FJ  = NT / 32;
    constexpr int ACH = MT / 32;
    constexpr int BCH = NT / 32;
    __shared__ __align__(16) unsigned short sA[MT * 64];
    __shared__ __align__(16) unsigned short sB[NT * 64];

    const int tid  = threadIdx.x;
    const int wave = tid >> 6, lane = tid & 63;
    const int lm   = lane & 15;
    const int quad = lane >> 4;
    const int wrow = (wave >> 1) * (MT / 2);
    const int wcol = (wave & 1) * (NT / 2);
    const int bm = blockIdx.y * MT, bn = blockIdx.x * NT;

    const int lrow = lane >> 3;
    const int lkb  = (lane & 7) ^ lrow;

    f32x4 acc[FI][FJ];
    #pragma unroll
    for (int i = 0; i < FI; ++i)
        #pragma unroll
        for (int j = 0; j < FJ; ++j) {
            acc[i][j][0] = 0.f; acc[i][j][1] = 0.f;
            acc[i][j][2] = 0.f; acc[i][j][3] = 0.f;
        }

    for (int k0 = 0; k0 < K; k0 += 64) {
        #pragma unroll
        for (int c = 0; c < ACH; ++c) {
            const int chunk = wave * ACH + c;
            const int row = chunk * 8 + lrow;
            async_copy16(&A[(size_t)(bm + row) * lda + k0 + lkb * 8],
                         &sA[chunk * 512 + lane * 8]);
        }
        #pragma unroll
        for (int c = 0; c < BCH; ++c) {
            const int chunk = wave * BCH + c;
            const int row = chunk * 8 + lrow;
            async_copy16(&BT[(size_t)(bn + row) * ldb + k0 + lkb * 8],
                         &sB[chunk * 512 + lane * 8]);
        }
        __syncthreads();

        #pragma unroll
        for (int ks = 0; ks < 2; ++ks) {
            bfrag af[FI], bf[FJ];
            #pragma unroll
            for (int i = 0; i < FI; ++i) {
                const int row = wrow + i * 16 + lm;
                const int slot = (ks * 4 + quad) ^ (row & 7);
                af[i] = *(const bfrag*)&sA[row * 64 + slot * 8];
            }
            #pragma unroll
            for (int j = 0; j < FJ; ++j) {
                const int row = wcol + j * 16 + lm;
                const int slot = (ks * 4 + quad) ^ (row & 7);
                bf[j] = *(const bfrag*)&sB[row * 64 + slot * 8];
            }
            #pragma unroll
            for (int i = 0; i < FI; ++i)
                #pragma unroll
                for (int j = 0; j < FJ; ++j)
                    acc[i][j] = __builtin_amdgcn_mfma_f32_16x16x32_bf16(
                        af[i], bf[j], acc[i][j], 0, 0, 0);
        }
        __syncthreads();
    }

    #pragma unroll
    for (int i = 0; i < FI; ++i)
        #pragma unroll
        for (int j = 0; j < FJ; ++j) {
            const int col = bn + wcol + j * 16 + lm;
            #pragma unroll
            for (int r = 0; r < 4; ++r) {
                const int row = bm + wrow + i * 16 + quad * 4 + r;
                float v = acc[i][j][r];
                if (split > 0) {
                    if (col < split) Cb0[(size_t)row * split + col] = f2bf(v);
                    else             Cb1[(size_t)row * split + (col - split)] = f2bf(v);
                } else {
                    C[(size_t)row * ldc + col] = v;
                }
            }
        }
}

// ---------------- fused prep: 3 transposes + x cast -------------------------
__global__ __launch_bounds__(256) void prep_fused(
    const float* __restrict__ W_in, const float* __restrict__ W_out,
    const float* __restrict__ W_dt, const float* __restrict__ x,
    unsigned short* __restrict__ wbT, unsigned short* __restrict__ wobT,
    unsigned short* __restrict__ wdtT, unsigned short* __restrict__ xb)
{
    __shared__ float tile[32][33];
    const int bx = blockIdx.x;
    const int tid = threadIdx.x;

    const float* in; unsigned short* out; int rows, cols, jt, it;
    if (bx < 4096)      { in = W_in;  out = wbT;  rows = 1024; cols = 4096;
                          jt = bx & 127; it = bx >> 7; }
    else if (bx < 6144) { int t = bx - 4096; in = W_out; out = wobT;
                          rows = 2048; cols = 1024; jt = t & 31; it = t >> 5; }
    else if (bx < 6272) { int t = bx - 6144; in = W_dt;  out = wdtT;
                          rows = 64;   cols = 2048; jt = t & 63; it = t >> 6; }
    else {
        int i = ((bx - 6272) * 256 + tid) * 4;
        float4 v = *(const float4*)&x[i];
        ushort4 o;
        o.x = f2bf(v.x); o.y = f2bf(v.y); o.z = f2bf(v.z); o.w = f2bf(v.w);
        *(ushort4*)&xb[i] = o;
        return;
    }
    const int j0 = jt * 32, i0 = it * 32;
    const int tx = tid & 31, ty = tid >> 5;
    #pragma unroll
    for (int k = 0; k < 4; ++k)
        tile[ty + 8 * k][tx] = in[(size_t)(i0 + ty + 8 * k) * cols + j0 + tx];
    __syncthreads();
    #pragma unroll
    for (int k = 0; k < 4; ++k)
        out[(size_t)(j0 + ty + 8 * k) * rows + i0 + tx] = f2bf(tile[tx][ty + 8 * k]);
}

// ---------------- split-K fp32 GEMM: part[ks] = u_c @ W_x (A is bf16) -------
#define SK_KS 128
__global__ __launch_bounds__(256) void gemm_f32_splitk(
    const unsigned short* __restrict__ A,    // [2048][2048] bf16
    const float* __restrict__ B,
    float* __restrict__ part)                // [16][2048][96]
{
    __shared__ __align__(16) float As[16][64];
    __shared__ __align__(16) float Bs[16][96];

    const int tid = threadIdx.x;
    const int mtile = blockIdx.x >> 4;
    const int kslice = blockIdx.x & 15;
    const int bm = mtile * 64;
    const int kbase = kslice * SK_KS;

    const int am = tid >> 2;
    const int ak = (tid & 3) << 2;

    const int ty = tid >> 4, tx = tid & 15;
    const int rm = ty << 2;
    const int rn = tx * 6;

    float acc[4][6] = {};

    for (int k0 = 0; k0 < SK_KS; k0 += 16) {
        ushort4 av = *(const ushort4*)&A[(size_t)(bm + am) * 2048 + kbase + k0 + ak];
        As[ak + 0][am] = bf2f(av.x);
        As[ak + 1][am] = bf2f(av.y);
        As[ak + 2][am] = bf2f(av.z);
        As[ak + 3][am] = bf2f(av.w);
        for (int i = tid; i < 384; i += 256) {
            int br = i / 24, bc = (i % 24) << 2;
            *(float4*)&Bs[br][bc] = *(const float4*)&B[(size_t)(kbase + k0 + br) * 96 + bc];
        }
        __syncthreads();

        #pragma unroll
        for (int k = 0; k < 16; ++k) {
            float4 a = *(const float4*)&As[k][rm];
            float b[6];
            #pragma unroll
            for (int j = 0; j < 6; ++j) b[j] = Bs[k][rn + j];
            #pragma unroll
            for (int j = 0; j < 6; ++j) {
                acc[0][j] += a.x * b[j];
                acc[1][j] += a.y * b[j];
                acc[2][j] += a.z * b[j];
                acc[3][j] += a.w * b[j];
            }
        }
        __syncthreads();
    }

    float* pout = part + (size_t)kslice * 196608;
    #pragma unroll
    for (int i = 0; i < 4; ++i) {
        float* crow = pout + (size_t)(bm + rm + i) * 96 + rn;
        #pragma unroll
        for (int j = 0; j < 6; ++j)
            crow[j] = acc[i][j];
    }
}

// ---- reduce 16 split-K partials -> xdbl f32; cols<64 also -> bf16 dtl ------
__global__ __launch_bounds__(256) void reduce_splitk(
    const float* __restrict__ part, float* __restrict__ xdbl,
    unsigned short* __restrict__ dtl)        // [2048][64] bf16
{
    int i = (blockIdx.x * 256 + threadIdx.x) * 4;   // < 196608
    float4 acc = {0.f, 0.f, 0.f, 0.f};
    #pragma unroll
    for (int s = 0; s < 16; ++s) {
        float4 v = *(const float4*)&part[(size_t)s * 196608 + i];
        acc.x += v.x; acc.y += v.y; acc.z += v.z; acc.w += v.w;
    }
    *(float4*)&xdbl[i] = acc;
    int row = i / 96, col = i % 96;
    if (col < 64) {
        ushort4 o;
        o.x = f2bf(acc.x); o.y = f2bf(acc.y);
        o.z = f2bf(acc.z); o.w = f2bf(acc.w);
        *(ushort4*)&dtl[(size_t)row * 64 + col] = o;
    }
}

// ---------------- depthwise causal conv(4) + bias + SiLU, x8 channels -------
__global__ __launch_bounds__(256) void conv_silu_kernel(
    const unsigned short* __restrict__ ub, const float* __restrict__ cw,
    const float* __restrict__ cb, unsigned short* __restrict__ uc)
{
    int idx = blockIdx.x * 256 + threadIdx.x;   // 0..524287
    int r  = idx >> 8;                          // row 0..2047
    int d0 = (idx & 255) * 8;                   // channel base
    int l  = r & 1023;

    float4 w[8];
    #pragma unroll
    for (int q = 0; q < 8; ++q) w[q] = *(const float4*)&cw[(d0 + q) * 4];

    float acc[8];
    #pragma unroll
    for (int q = 0; q < 8; ++q) acc[q] = cb[d0 + q];

    const unsigned short* up = ub + (size_t)r * 2048 + d0;
    #pragma unroll
    for (int j = 0; j < 4; ++j) {
        int lj = l - 3 + j;
        if (lj >= 0) {
            const unsigned short* rp = up + (ptrdiff_t)(j - 3) * 2048;
            ushort4 a = *(const ushort4*)&rp[0];
            ushort4 b4 = *(const ushort4*)&rp[4];
            float uv[8] = { bf2f(a.x), bf2f(a.y), bf2f(a.z), bf2f(a.w),
                            bf2f(b4.x), bf2f(b4.y), bf2f(b4.z), bf2f(b4.w) };
            #pragma unroll
            for (int q = 0; q < 8; ++q)
                acc[q] += uv[q] * ((const float*)&w[q])[j];
        }
    }
    ushort4 o0, o1;
    float s;
    s = 1.f / (1.f + expf(-acc[0])); o0.x = f2bf(acc[0] * s);
    s = 1.f / (1.f + expf(-acc[1])); o0.y = f2bf(acc[1] * s);
    s = 1.f / (1.f + expf(-acc[2])); o0.z = f2bf(acc[2] * s);
    s = 1.f / (1.f + expf(-acc[3])); o0.w = f2bf(acc[3] * s);
    s = 1.f / (1.f + expf(-acc[4])); o1.x = f2bf(acc[4] * s);
    s = 1.f / (1.f + expf(-acc[5])); o1.y = f2bf(acc[5] * s);
    s = 1.f / (1.f + expf(-acc[6])); o1.z = f2bf(acc[6] * s);
    s = 1.f / (1.f + expf(-acc[7])); o1.w = f2bf(acc[7] * s);
    *(ushort4*)&uc[(size_t)r * 2048 + d0]     = o0;
    *(ushort4*)&uc[(size_t)r * 2048 + d0 + 4] = o1;
}

// ---------------------------------------------------------------------------
// Scan passes with FUSED in-block dt MFMA:
// dt[t][d] = softplus( dtl[row][0:64] . wdtT[d][0:64] + b_dt[d] )
// Per block: 32 t x 256 d via 16x16x32 MFMA (wave covers 32t x 64d, 16 MFMA).
// ---------------------------------------------------------------------------
__device__ __forceinline__ void compute_dt_tile(
    const unsigned short* __restrict__ wdtT, const float* __restrict__ b_dt,
    const unsigned short (*sdtl)[72], unsigned short (*sdt)[256],
    int dbase, int tid)
{
    const int wave = tid >> 6, lane = tid & 63;
    const int lm = lane & 15, quad = lane >> 4;

    f32x4 dacc[2][4];
    #pragma unroll
    for (int mi = 0; mi < 2; ++mi)
        #pragma unroll
        for (int j = 0; j < 4; ++j) {
            dacc[mi][j][0] = 0.f; dacc[mi][j][1] = 0.f;
            dacc[mi][j][2] = 0.f; dacc[mi][j][3] = 0.f;
        }

    #pragma unroll
    for (int kc = 0; kc < 2; ++kc) {
        bfrag a[2], bw[4];
        #pragma unroll
        for (int mi = 0; mi < 2; ++mi)
            a[mi] = *(const bfrag*)&sdtl[mi * 16 + lm][kc * 32 + quad * 8];
        #pragma unroll
        for (int j = 0; j < 4; ++j) {
            const int dg = dbase + wave * 64 + j * 16 + lm;
            bw[j] = *(const bfrag*)&wdtT[(size_t)dg * 64 + kc * 32 + quad * 8];
        }
        #pragma unroll
        for (int mi = 0; mi < 2; ++mi)
            #pragma unroll
            for (int j = 0; j < 4; ++j)
                dacc[mi][j] = __builtin_amdgcn_mfma_f32_16x16x32_bf16(
                    a[mi], bw[j], dacc[mi][j], 0, 0, 0);
    }

    #pragma unroll
    for (int j = 0; j < 4; ++j) {
        const int dl = wave * 64 + j * 16 + lm;
        const float bb = b_dt[dbase + dl];
        #pragma unroll
        for (int mi = 0; mi < 2; ++mi)
            #pragma unroll
            for (int r = 0; r < 4; ++r) {
                const int t = mi * 16 + quad * 4 + r;
                float v = dacc[mi][j][r] + bb;
                v = (v > 20.f) ? v : logf(1.f + expf(v));   // softplus
                sdt[t][dl] = f2bf(v);
            }
    }
}

__global__ __launch_bounds__(256) void scan_pass1(
    const unsigned short* __restrict__ uc,
    const unsigned short* __restrict__ dtl,   // [2048][64] bf16
    const unsigned short* __restrict__ wdtT,  // [2048][64] bf16
    const float* __restrict__ b_dt,
    const float* __restrict__ xdbl,
    const float* __restrict__ A_log,
    float* __restrict__ Hend,         // [2][CF][2048][16]
    float* __restrict__ Sdt)          // [2][CF][2048]
{
    __shared__ __align__(16) unsigned short su  [CLEN][256];
    __shared__ __align__(16) unsigned short sdt [CLEN][256];
    __shared__ __align__(16) unsigned short sdtl[CLEN][72];   // +8 pad
    __shared__ float sB[CLEN][16];
    const int tid = threadIdx.x;
    const int bx  = blockIdx.x;
    const int c   = bx & (CF - 1);
    const int g   = (bx >> 5) & 7;
    const int b   = bx >> 8;
    const int dbase = g * 256;
    const int d   = dbase + tid;
    const size_t rowbase = (size_t)b * 1024 + c * CLEN;

    #pragma unroll
    for (int q = 0; q < 4; ++q) {
        int i = q * 256 + tid;
        int row = i >> 5, off = (i & 31) * 8;
        *(float4*)&su[row][off] = *(const float4*)&uc[(rowbase + row) * 2048 + dbase + off];
    }
    #pragma unroll
    for (int q = 0; q < 2; ++q) {
        int i = q * 256 + tid;                 // 512 chunks of 4 shorts
        int row = i >> 4, col = (i & 15) * 4;
        *(ushort4*)&sdtl[row][col] = *(const ushort4*)&dtl[(rowbase + row) * 64 + col];
    }
    for (int i = tid; i < CLEN * 16; i += 256) {
        int tt = i >> 4, nn = i & 15;
        sB[tt][nn] = xdbl[(rowbase + tt) * 96 + 64 + nn];
    }

    float A2[16];
    {
        float al[16];
        #pragma unroll
        for (int q = 0; q < 4; ++q)
            *(float4*)&al[4 * q] = *(const float4*)&A_log[(size_t)d * 16 + 4 * q];
        #pragma unroll
        for (int n = 0; n < 16; ++n) A2[n] = -expf(al[n]) * 1.44269504f;
    }
    __syncthreads();

    compute_dt_tile(wdtT, b_dt, sdtl, sdt, dbase, tid);
    __syncthreads();

    float h[16];
    #pragma unroll
    for (int n = 0; n < 16; ++n) h[n] = 0.f;
    float sdtv = 0.f;

    #pragma unroll 4
    for (int t = 0; t < CLEN; ++t) {
        float dtv = bf2f(sdt[t][tid]);
        float uv  = bf2f(su [t][tid]);
        sdtv += dtv;
        float dtu = dtv * uv;
        float bl[16];
        #pragma unroll
        for (int q = 0; q < 4; ++q)
            *(float4*)&bl[4 * q] = *(const float4*)&sB[t][4 * q];
        #pragma unroll
        for (int n = 0; n < 16; ++n)
            h[n] = exp2f(dtv * A2[n]) * h[n] + dtu * bl[n];
    }

    size_t base = ((size_t)(b * CF + c) * 2048 + d) * 16;
    #pragma unroll
    for (int q = 0; q < 4; ++q)
        *(float4*)&Hend[base + 4 * q] = *(float4*)&h[4 * q];
    Sdt[(size_t)(b * CF + c) * 2048 + d] = sdtv;
}

__global__ __launch_bounds__(256) void scan_pass2(
    const float* __restrict__ Hend, const float* __restrict__ Sdt,
    const float* __restrict__ A_log, float* __restrict__ Hin)
{
    int gid = blockIdx.x * 256 + threadIdx.x;   // 0..65535
    int b = gid >> 15;
    int rest = gid & 32767;                     // d*16+n
    int d = rest >> 4;
    float A2 = -expf(A_log[rest]) * 1.44269504f;
    float H = 0.f;
    #pragma unroll
    for (int c = 0; c < CF; ++c) {
        size_t sidx = (size_t)(b * CF + c) * 2048 + d;
        size_t idx  = ((size_t)(b * CF + c) << 15) + rest;
        Hin[idx] = H;
        H = exp2f(A2 * Sdt[sidx]) * H + Hend[idx];
    }
}

__global__ __launch_bounds__(256) void scan_pass3(
    const unsigned short* __restrict__ uc,
    const unsigned short* __restrict__ dtl,
    const unsigned short* __restrict__ wdtT,
    const float* __restrict__ b_dt,
    const unsigned short* __restrict__ zb,  // [2048][2048] bf16
    const float* __restrict__ xdbl,
    const float* __restrict__ A_log,
    const float* __restrict__ Dvec,
    const float* __restrict__ Hin,
    unsigned short* __restrict__ yb)
{
    __shared__ __align__(16) unsigned short su  [CLEN][256];
    __shared__ __align__(16) unsigned short sdt [CLEN][256];
    __shared__ __align__(16) unsigned short sz  [CLEN][256];  // z in, y out
    __shared__ __align__(16) unsigned short sdtl[CLEN][72];
    __shared__ float sBC[CLEN][32];
    const int tid = threadIdx.x;
    const int bx  = blockIdx.x;
    const int c   = bx & (CF - 1);
    const int g   = (bx >> 5) & 7;
    const int b   = bx >> 8;
    const int dbase = g * 256;
    const int d   = dbase + tid;
    const size_t rowbase = (size_t)b * 1024 + c * CLEN;

    #pragma unroll
    for (int q = 0; q < 4; ++q) {
        int i = q * 256 + tid;
        int row = i >> 5, off = (i & 31) * 8;
        size_t gaddr = (rowbase + row) * 2048 + dbase + off;
        *(float4*)&su[row][off] = *(const float4*)&uc[gaddr];
        *(float4*)&sz[row][off] = *(const float4*)&zb[gaddr];
    }
    #pragma unroll
    for (int q = 0; q < 2; ++q) {
        int i = q * 256 + tid;
        int row = i >> 4, col = (i & 15) * 4;
        *(ushort4*)&sdtl[row][col] = *(const ushort4*)&dtl[(rowbase + row) * 64 + col];
    }
    for (int i = tid; i < CLEN * 32; i += 256) {
        int tt = i >> 5, j = i & 31;
        sBC[tt][j] = xdbl[(rowbase + tt) * 96 + 64 + j];
    }

    float A2[16];
    {
        float al[16];
        #pragma unroll
        for (int q = 0; q < 4; ++q)
            *(float4*)&al[4 * q] = *(const float4*)&A_log[(size_t)d * 16 + 4 * q];
        #pragma unroll
        for (int n = 0; n < 16; ++n) A2[n] = -expf(al[n]) * 1.44269504f;
    }
    const float Dd = Dvec[d];

    float h[16];
    {
        size_t base = ((size_t)(b * CF + c) * 2048 + d) * 16;
        #pragma unroll
        for (int q = 0; q < 4; ++q)
            *(float4*)&h[4 * q] = *(const float4*)&Hin[base + 4 * q];
    }
    __syncthreads();

    compute_dt_tile(wdtT, b_dt, sdtl, sdt, dbase, tid);
    __syncthreads();

    #pragma unroll 4
    for (int t = 0; t < CLEN; ++t) {
        float dtv = bf2f(sdt[t][tid]);
        float uv  = bf2f(su [t][tid]);
        float zv  = bf2f(sz [t][tid]);
        float dtu = dtv * uv;
        float bl[16], cl[16];
        #pragma unroll
        for (int q = 0; q < 4; ++q) {
            *(float4*)&bl[4 * q] = *(const float4*)&sBC[t][4 * q];
            *(float4*)&cl[4 * q] = *(const float4*)&sBC[t][16 + 4 * q];
        }
        float acc = uv * Dd;
        #pragma unroll
        for (int n = 0; n < 16; ++n) {
            h[n] = exp2f(dtv * A2[n]) * h[n] + dtu * bl[n];
            acc += h[n] * cl[n];
        }
        float yv = acc * zv / (1.f + expf(-zv));
        sz[t][tid] = f2bf(yv);              // reuse z slot
    }
    __syncthreads();

    #pragma unroll
    for (int q = 0; q < 4; ++q) {
        int i = q * 256 + tid;
        int row = i >> 5, off = (i & 31) * 8;
        size_t gaddr = (rowbase + row) * 2048 + dbase + off;
        *(float4*)&yb[gaddr] = *(const float4*)&sz[row][off];
    }
}

extern "C" void kernel_launch(void* const* d_in, const int* in_sizes, int n_in,
                              void* d_out, int out_size, void* d_ws, size_t ws_size,
                              hipStream_t stream)
{
    const float* x      = (const float*)d_in[0];
    const float* W_in   = (const float*)d_in[1];
    const float* conv_w = (const float*)d_in[2];
    const float* conv_b = (const float*)d_in[3];
    const float* W_x    = (const float*)d_in[4];
    const float* W_dt   = (const float*)d_in[5];
    const float* b_dt   = (const float*)d_in[6];
    const float* A_log  = (const float*)d_in[7];
    const float* Dv     = (const float*)d_in[8];
    const float* W_out  = (const float*)d_in[9];
    float* out = (float*)d_out;

    float* ws = (float*)d_ws;
    unsigned short* ub  = (unsigned short*)ws;        // [2048][2048] bf16 (u_pre)
    unsigned short* uc  = ub + 4194304;               // [2048][2048] bf16
    float* xdbl = ws + 4194304;                       // [2048][96] f32
    unsigned short* dtl = (unsigned short*)(xdbl + 196608);  // [2048][64] bf16
    float* Hend = xdbl + 196608 + 65536;              // 2097152 f32
    float* Hin  = Hend + 2097152;                     // 2097152 f32
    float* Sdt  = Hin + 2097152;                      // 131072 f32
    float* part = Hend;                               // ALIAS: [16][2048][96]
    unsigned short* zb   = (unsigned short*)(Sdt + 131072);  // [2048][2048] bf16
    unsigned short* xb   = zb + 4194304;              // [2048][1024] bf16
    unsigned short* wbT  = xb + 2097152;              // [4096][1024] bf16
    unsigned short* wobT = wbT + 4194304;             // [1024][2048] bf16
    unsigned short* wdtT = wobT + 2097152;            // [2048][64] bf16
    unsigned short* yb   = wbT;                       // aliases wbT

    dim3 blk(256);

    // 0. fused prep
    prep_fused<<<8320, blk, 0, stream>>>(W_in, W_out, W_dt, x,
                                         wbT, wobT, wdtT, xb);

    // 1. xz = x @ W_in   (bf16 MFMA, 128x128 -> 512 blocks; u/z bf16)
    gemm_bf16_v2<128, 128><<<dim3(32, 16), blk, 0, stream>>>(
        xb, wbT, nullptr, ub, zb, 1024, 1024, 1024, 2048, 2048);

    // 2. u_c = silu(conv(u) + cb)   (x8 vectorized)
    conv_silu_kernel<<<2048, blk, 0, stream>>>(ub, conv_w, conv_b, uc);

    // 3. x_dbl = u_c @ W_x   (split-K + reduce; emits bf16 dtl)
    gemm_f32_splitk<<<512, blk, 0, stream>>>(uc, W_x, part);
    reduce_splitk<<<192, blk, 0, stream>>>(part, xdbl, dtl);

    // 4+5. scan with fused in-block dt MFMA (dtb eliminated)
    scan_pass1<<<512, blk, 0, stream>>>(uc, dtl, wdtT, b_dt, xdbl, A_log, Hend, Sdt);
    scan_pass2<<<256, blk, 0, stream>>>(Hend, Sdt, A_log, Hin);
    scan_pass3<<<512, blk, 0, stream>>>(uc, dtl, wdtT, b_dt, zb, xdbl, A_log, Dv, Hin, yb);

    // 6. out = y @ W_out   (bf16 MFMA, 64x64 -> 512 blocks)
    gemm_bf16_v2<64, 64><<<dim3(16, 32), blk, 0, stream>>>(
        yb, wobT, out, nullptr, nullptr, 2048, 2048, 2048, 1024, 0);
}